// Round 2
// baseline (478.820 us; speedup 1.0000x reference)
//
#include <hip/hip_runtime.h>
#include <hip/hip_bf16.h>
#include <stdint.h>
#include <stddef.h>

#define NV 2048
#define NE 8192
#define KSPLIT 8            // gemm1 K-split: 136*8 = 1088 blocks ~ 4.25/CU
#define KCHUNK (NE / KSPLIT)
#define KSPLIT2 16          // gemm2 K-split: 16*16 = 256 blocks
#define KCHUNK2 (NV / KSPLIT2)

typedef __bf16 bf16_t;
typedef __bf16 bf16x4 __attribute__((ext_vector_type(4)));
typedef __bf16 bf16x8 __attribute__((ext_vector_type(8)));
typedef float f32x4 __attribute__((ext_vector_type(4)));
typedef float f32x16 __attribute__((ext_vector_type(16)));

__device__ static inline void load_lds16(const void* g, void* lds) {
  __builtin_amdgcn_global_load_lds(
      (const __attribute__((address_space(1))) void*)g,
      (__attribute__((address_space(3))) void*)lds,
      16, 0, 0);
}

__device__ static inline void tile_decode(int tile, int& bi, int& bj) {
  int b = (int)((sqrtf(8.f * tile + 1.f) - 1.f) * 0.5f);
  while ((b + 1) * (b + 2) / 2 <= tile) b++;
  while (b * (b + 1) / 2 > tile) b--;
  bi = b;
  bj = tile - b * (b + 1) / 2;
}

// w[e] = dot(H_e[e,:], p[:])   one wave per row
__global__ void k_w(const float* __restrict__ He, const float* __restrict__ p,
                    float* __restrict__ w) {
  int wave = threadIdx.x >> 6;
  int lane = threadIdx.x & 63;
  int e = blockIdx.x * 4 + wave;
  float v = He[(size_t)e * 128 + lane] * p[lane]
          + He[(size_t)e * 128 + 64 + lane] * p[64 + lane];
#pragma unroll
  for (int off = 32; off > 0; off >>= 1) v += __shfl_down(v, off, 64);
  if (lane == 0) w[e] = v;
}

// A[i,e] = bf16(T[i,e]*w[e]);  B[i,e] = bf16(T[i,e])
__global__ void k_conv(const float* __restrict__ T, const float* __restrict__ w,
                       bf16_t* __restrict__ A, bf16_t* __restrict__ B) {
  size_t idx = (size_t)blockIdx.x * 256 + threadIdx.x;  // one float4 each
  size_t base = idx * 4;
  int col = (int)(base & (NE - 1));
  f32x4 t = *(const f32x4*)(T + base);
  f32x4 w4 = *(const f32x4*)(w + col);
  bf16x4 a, b;
  a.x = (bf16_t)(t.x * w4.x); a.y = (bf16_t)(t.y * w4.y);
  a.z = (bf16_t)(t.z * w4.z); a.w = (bf16_t)(t.w * w4.w);
  b.x = (bf16_t)t.x; b.y = (bf16_t)t.y; b.z = (bf16_t)t.z; b.w = (bf16_t)t.w;
  *(bf16x4*)(A + base) = a;
  *(bf16x4*)(B + base) = b;
}

// HWt[o,j] = bf16( sum_k H_v[j,k] * weight[k,o] )   (transposed, bf16)
__global__ void k_hw(const float* __restrict__ Hv, const float* __restrict__ Wt,
                     bf16_t* __restrict__ HWt) {
  int t = blockIdx.x * 256 + threadIdx.x;
  int o = t & 127, j = t >> 7;
  const float* hv = Hv + (size_t)j * 128;
  float acc = 0.f;
#pragma unroll 4
  for (int k = 0; k < 128; ++k) acc += hv[k] * Wt[k * 128 + o];
  HWt[(size_t)o * NV + j] = (bf16_t)acc;
}

// P[tile][split][128][128](bf16) = partial over K chunk; lower-tri tiles only.
// grid (136, KSPLIT), 256 threads, 128x128 tile, BK=64, 32x32x16 MFMA,
// XOR-swizzled LDS. launch_bounds(256,4): cap VGPR<=128 -> 4 blocks/CU
// (128 KiB LDS of 160) so the vmcnt(0)+barrier drain is TLP-hidden (m114 regime).
__global__ void __launch_bounds__(256, 4)
k_gemm1(const bf16_t* __restrict__ A, const bf16_t* __restrict__ B,
        bf16_t* __restrict__ P) {
  __shared__ bf16_t As[128 * 64];
  __shared__ bf16_t Bs[128 * 64];
  const int t = threadIdx.x;
  const int lane = t & 63;
  const int wv = t >> 6;
  const int wm = wv >> 1, wn = wv & 1;

  int bi, bj;
  tile_decode(blockIdx.x, bi, bj);
  const int i0 = bi * 128, j0 = bj * 128;
  const int kbeg = blockIdx.y * KCHUNK;
  bf16_t* Mp = P + ((size_t)blockIdx.x * KSPLIT + blockIdx.y) * 16384;

  f32x16 acc[2][2] = {};

  // staging: physical 8-elem slot s=(t&7) of row r holds logical k-block (s+r)&7
  const int lrow = t >> 3;                        // 0..31 (+32 per it)
  const int cb = ((t & 7) + lrow) & 7;            // swizzled global k-block
  const bf16_t* Ag = A + (size_t)(i0 + lrow) * NE + cb * 8;
  const bf16_t* Bg = B + (size_t)(j0 + lrow) * NE + cb * 8;

  for (int k0 = kbeg; k0 < kbeg + KCHUNK; k0 += 64) {
    __syncthreads();
#pragma unroll
    for (int it = 0; it < 4; ++it) {
      load_lds16(Ag + (size_t)(it * 32) * NE + k0, (char*)As + (it * 256 + t) * 16);
      load_lds16(Bg + (size_t)(it * 32) * NE + k0, (char*)Bs + (it * 256 + t) * 16);
    }
    __syncthreads();
#pragma unroll
    for (int kk = 0; kk < 64; kk += 16) {
      bf16x8 af[2], bfr[2];
#pragma unroll
      for (int mt = 0; mt < 2; ++mt) {
        int row = wm * 64 + mt * 32 + (lane & 31);
        int sw = (((kk >> 3) + (lane >> 5)) - row) & 7;
        af[mt] = *(const bf16x8*)&As[row * 64 + sw * 8];
      }
#pragma unroll
      for (int nt = 0; nt < 2; ++nt) {
        int row = wn * 64 + nt * 32 + (lane & 31);
        int sw = (((kk >> 3) + (lane >> 5)) - row) & 7;
        bfr[nt] = *(const bf16x8*)&Bs[row * 64 + sw * 8];
      }
#pragma unroll
      for (int mt = 0; mt < 2; ++mt)
#pragma unroll
        for (int nt = 0; nt < 2; ++nt)
          acc[mt][nt] = __builtin_amdgcn_mfma_f32_32x32x16_bf16(af[mt], bfr[nt], acc[mt][nt], 0, 0, 0);
    }
  }

  // C/D layout (32x32): col = lane&31, row = (reg&3) + 8*(reg>>2) + 4*(lane>>5)
#pragma unroll
  for (int mt = 0; mt < 2; ++mt) {
#pragma unroll
    for (int nt = 0; nt < 2; ++nt) {
      int tc = wn * 64 + nt * 32 + (lane & 31);
#pragma unroll
      for (int reg = 0; reg < 16; ++reg) {
        int tr = wm * 64 + mt * 32 + (reg & 3) + 8 * (reg >> 2) + 4 * (lane >> 5);
        Mp[tr * 128 + tc] = (bf16_t)acc[mt][nt][reg];
      }
    }
  }
}

// adjA_bf[i,j] = bf16( (i==j ? 1 : sum_s P[tile][s][i,j]) * adj_v[i,j] ), both triangles.
__global__ void k_mask(const bf16_t* __restrict__ P, const float* __restrict__ adj_v,
                       bf16_t* __restrict__ adjA) {
  __shared__ float Ms[128 * 129];
  const int t = threadIdx.x;
  int bi, bj;
  tile_decode(blockIdx.x, bi, bj);
  const int i0 = bi * 128, j0 = bj * 128;
  const bool diag = (bi == bj);
  const bf16_t* Pt = P + (size_t)blockIdx.x * (KSPLIT * 16384);
#pragma unroll 2
  for (int c = 0; c < 8; ++c) {
    int e0 = (c * 256 + t) * 8;
    int r = e0 >> 7, col = e0 & 127;
    float v[8] = {};
#pragma unroll
    for (int s = 0; s < KSPLIT; ++s) {
      bf16x8 pv = *(const bf16x8*)(Pt + s * 16384 + e0);
#pragma unroll
      for (int u = 0; u < 8; ++u) v[u] += (float)pv[u];
    }
    size_t g = (size_t)(i0 + r) * NV + j0 + col;
    f32x4 av0 = *(const f32x4*)(adj_v + g);
    f32x4 av1 = *(const f32x4*)(adj_v + g + 4);
    bf16x8 outv;
#pragma unroll
    for (int u = 0; u < 8; ++u) {
      float vv = (diag && r == col + u) ? 1.0f : v[u];
      outv[u] = (bf16_t)(vv * (u < 4 ? av0[u] : av1[u - 4]));
    }
    *(bf16x8*)(adjA + g) = outv;
    if (!diag) {
#pragma unroll
      for (int u = 0; u < 8; ++u) Ms[(col + u) * 129 + r] = v[u];
    }
  }
  if (diag) return;
  __syncthreads();
#pragma unroll 2
  for (int c = 0; c < 8; ++c) {
    int e0 = (c * 256 + t) * 8;
    int r = e0 >> 7, col = e0 & 127;
    size_t g = (size_t)(j0 + r) * NV + i0 + col;
    f32x4 av0 = *(const f32x4*)(adj_v + g);
    f32x4 av1 = *(const f32x4*)(adj_v + g + 4);
    bf16x8 outv;
#pragma unroll
    for (int u = 0; u < 8; ++u)
      outv[u] = (bf16_t)(Ms[r * 129 + col + u] * (u < 4 ? av0[u] : av1[u - 4]));
    *(bf16x8*)(adjA + g) = outv;
  }
}

// P2[split][i][o] = partial of adjA @ HW^T over K chunk of KCHUNK2. grid (16, KSPLIT2).
__global__ void k_gemm2(const bf16_t* __restrict__ adjA, const bf16_t* __restrict__ HWt,
                        float* __restrict__ P2) {
  __shared__ bf16_t As[128 * 64];
  __shared__ bf16_t Bs[128 * 64];
  const int t = threadIdx.x;
  const int lane = t & 63;
  const int wv = t >> 6;
  const int wm = wv >> 1, wn = wv & 1;
  const int i0 = blockIdx.x * 128;
  const int kbeg = blockIdx.y * KCHUNK2;
  float* Pp = P2 + (size_t)blockIdx.y * (NV * 128);

  f32x4 acc[4][4] = {};

  const int lrow = t >> 3;
  const int cb = ((t & 7) + lrow) & 7;
  const bf16_t* Ag = adjA + (size_t)(i0 + lrow) * NV + cb * 8;
  const bf16_t* Bg = HWt + (size_t)lrow * NV + cb * 8;

  for (int k0 = kbeg; k0 < kbeg + KCHUNK2; k0 += 64) {
    __syncthreads();
#pragma unroll
    for (int it = 0; it < 4; ++it) {
      load_lds16(Ag + (size_t)(it * 32) * NV + k0, (char*)As + (it * 256 + t) * 16);
      load_lds16(Bg + (size_t)(it * 32) * NV + k0, (char*)Bs + (it * 256 + t) * 16);
    }
    __syncthreads();
#pragma unroll
    for (int kk = 0; kk < 64; kk += 32) {
      bf16x8 af[4], bfr[4];
#pragma unroll
      for (int mt = 0; mt < 4; ++mt) {
        int row = wm * 64 + mt * 16 + (lane & 15);
        int sw = (((kk >> 3) + (lane >> 4)) - row) & 7;
        af[mt] = *(const bf16x8*)&As[row * 64 + sw * 8];
      }
#pragma unroll
      for (int nt = 0; nt < 4; ++nt) {
        int row = wn * 64 + nt * 16 + (lane & 15);
        int sw = (((kk >> 3) + (lane >> 4)) - row) & 7;
        bfr[nt] = *(const bf16x8*)&Bs[row * 64 + sw * 8];
      }
#pragma unroll
      for (int mt = 0; mt < 4; ++mt)
#pragma unroll
        for (int nt = 0; nt < 4; ++nt)
          acc[mt][nt] = __builtin_amdgcn_mfma_f32_16x16x32_bf16(af[mt], bfr[nt], acc[mt][nt], 0, 0, 0);
    }
  }

#pragma unroll
  for (int mt = 0; mt < 4; ++mt) {
#pragma unroll
    for (int nt = 0; nt < 4; ++nt) {
      int gc = wn * 64 + nt * 16 + (lane & 15);   // output col o (0..127)
#pragma unroll
      for (int r = 0; r < 4; ++r) {
        int gr = i0 + wm * 64 + mt * 16 + (lane >> 4) * 4 + r;
        Pp[(size_t)gr * 128 + gc] = acc[mt][nt][r];
      }
    }
  }
}

// blocks [0,256):   out[i,o] = sum_s P2[s][i][o] + bias[o]
// blocks [256,1280): out2 = copy of H_e (fused passthrough, replaces memcpy)
__global__ void k_bias(const float* __restrict__ P2, const float* __restrict__ bias,
                       const float* __restrict__ He, float* __restrict__ out) {
  int b = blockIdx.x;
  if (b < 256) {
    int idx = (b * 256 + threadIdx.x) * 4;  // 2048*128/4 = 65536 threads
    f32x4 acc = {};
#pragma unroll
    for (int s = 0; s < KSPLIT2; ++s)
      acc += *(const f32x4*)(P2 + (size_t)s * NV * 128 + idx);
    f32x4 bb = *(const f32x4*)(bias + (idx & 127));
    *(f32x4*)(out + idx) = acc + bb;
  } else {
    size_t idx = ((size_t)(b - 256) * 256 + threadIdx.x) * 4;
    *(f32x4*)(out + (size_t)NV * 128 + idx) = *(const f32x4*)(He + idx);
  }
}

extern "C" void kernel_launch(void* const* d_in, const int* in_sizes, int n_in,
                              void* d_out, int out_size, void* d_ws, size_t ws_size,
                              hipStream_t stream) {
  const float* Hv     = (const float*)d_in[0];
  const float* He     = (const float*)d_in[1];
  // d_in[2] = adj_e : UNUSED in the node_layer branch
  const float* adj_v  = (const float*)d_in[3];
  const float* T      = (const float*)d_in[4];
  const float* weight = (const float*)d_in[5];
  const float* p      = (const float*)d_in[6];
  const float* bias   = (const float*)d_in[7];
  float* out = (float*)d_out;

  char* ws = (char*)d_ws;
  bf16_t* A_bf  = (bf16_t*)ws;                       // [0, 32M)
  bf16_t* B_bf  = (bf16_t*)(ws + 33554432);          // [32M, 64M)
  bf16_t* P1    = (bf16_t*)(ws + 67108864);          // 136*8*16384*2 = 35.7 MB
  bf16_t* adjAb = (bf16_t*)(ws + 104857600);         // [100M, +8 MB)
  float*  P2    = (float*)(ws + 113246208);          // [108M, +16 MB)
  bf16_t* HWt   = (bf16_t*)(ws + 130023424);         // [124M, +512 KB)
  float*  w     = (float*)(ws + 130547712);          // [124.5M, +32 KB)

  k_w<<<NE / 4, 256, 0, stream>>>(He, p, w);
  k_conv<<<(NV * NE / 4) / 256, 256, 0, stream>>>(T, w, A_bf, B_bf);
  k_hw<<<(NV * 128) / 256, 256, 0, stream>>>(Hv, weight, HWt);
  dim3 g1(136, KSPLIT);
  k_gemm1<<<g1, 256, 0, stream>>>(A_bf, B_bf, P1);
  k_mask<<<136, 256, 0, stream>>>(P1, adj_v, adjAb);
  dim3 g2(NV / 128, KSPLIT2);
  k_gemm2<<<g2, 256, 0, stream>>>(adjAb, HWt, P2);
  k_bias<<<256 + (NE * 128) / (4 * 256), 256, 0, stream>>>(P2, bias, He, out);
}

// Round 3
// 456.321 us; speedup vs baseline: 1.0493x; 1.0493x over previous
//
#include <hip/hip_runtime.h>
#include <hip/hip_bf16.h>
#include <stdint.h>
#include <stddef.h>

#define NV 2048
#define NE 8192
#define NSPLIT1 7           // gemm1 K-splits: 36 super-tiles * 7 = 252 blocks = 1 round on 256 CUs
#define KSPLIT2 16          // gemm2 K-split: 16*16 = 256 blocks
#define KCHUNK2 (NV / KSPLIT2)

typedef __bf16 bf16_t;
typedef __bf16 bf16x4 __attribute__((ext_vector_type(4)));
typedef __bf16 bf16x8 __attribute__((ext_vector_type(8)));
typedef float f32x4 __attribute__((ext_vector_type(4)));
typedef float f32x16 __attribute__((ext_vector_type(16)));

__device__ static inline void load_lds16(const void* g, void* lds) {
  __builtin_amdgcn_global_load_lds(
      (const __attribute__((address_space(1))) void*)g,
      (__attribute__((address_space(3))) void*)lds,
      16, 0, 0);
}

__device__ static inline void tile_decode(int tile, int& bi, int& bj) {
  int b = (int)((sqrtf(8.f * tile + 1.f) - 1.f) * 0.5f);
  while ((b + 1) * (b + 2) / 2 <= tile) b++;
  while (b * (b + 1) / 2 > tile) b--;
  bi = b;
  bj = tile - b * (b + 1) / 2;
}

// w[e] = dot(H_e[e,:], p[:])   one wave per row
__global__ void k_w(const float* __restrict__ He, const float* __restrict__ p,
                    float* __restrict__ w) {
  int wave = threadIdx.x >> 6;
  int lane = threadIdx.x & 63;
  int e = blockIdx.x * 4 + wave;
  float v = He[(size_t)e * 128 + lane] * p[lane]
          + He[(size_t)e * 128 + 64 + lane] * p[64 + lane];
#pragma unroll
  for (int off = 32; off > 0; off >>= 1) v += __shfl_down(v, off, 64);
  if (lane == 0) w[e] = v;
}

// A[i,e] = bf16(T[i,e]*w[e]);  B[i,e] = bf16(T[i,e])
__global__ void k_conv(const float* __restrict__ T, const float* __restrict__ w,
                       bf16_t* __restrict__ A, bf16_t* __restrict__ B) {
  size_t idx = (size_t)blockIdx.x * 256 + threadIdx.x;  // one float4 each
  size_t base = idx * 4;
  int col = (int)(base & (NE - 1));
  f32x4 t = *(const f32x4*)(T + base);
  f32x4 w4 = *(const f32x4*)(w + col);
  bf16x4 a, b;
  a.x = (bf16_t)(t.x * w4.x); a.y = (bf16_t)(t.y * w4.y);
  a.z = (bf16_t)(t.z * w4.z); a.w = (bf16_t)(t.w * w4.w);
  b.x = (bf16_t)t.x; b.y = (bf16_t)t.y; b.z = (bf16_t)t.z; b.w = (bf16_t)t.w;
  *(bf16x4*)(A + base) = a;
  *(bf16x4*)(B + base) = b;
}

// HWt[o,j] = bf16( sum_k H_v[j,k] * weight[k,o] )   (transposed, bf16)
__global__ void k_hw(const float* __restrict__ Hv, const float* __restrict__ Wt,
                     bf16_t* __restrict__ HWt) {
  int t = blockIdx.x * 256 + threadIdx.x;
  int o = t & 127, j = t >> 7;
  const float* hv = Hv + (size_t)j * 128;
  float acc = 0.f;
#pragma unroll 4
  for (int k = 0; k < 128; ++k) acc += hv[k] * Wt[k * 128 + o];
  HWt[(size_t)o * NV + j] = (bf16_t)acc;
}

// P[super36][split7][256][256](bf16) partials of T*w @ T^T, lower-tri 256-super-tiles.
// grid (36, 7), 512 threads (8 waves, 2x4), BK=64, 32x32x16 MFMA, XOR-slot LDS swizzle.
// 256^2 tile halves staged LDS bytes vs 128^2 (302 MB vs 570 MB) -- staging-BW-bound regime.
// Uneven K chunks 6x1152 + 1280 keep the grid at 252 blocks = one round on 256 CUs.
__global__ void __launch_bounds__(512, 2)
k_gemm1(const bf16_t* __restrict__ A, const bf16_t* __restrict__ B,
        bf16_t* __restrict__ P) {
  __shared__ bf16_t As[256 * 64];
  __shared__ bf16_t Bs[256 * 64];
  const int t = threadIdx.x;        // 0..511
  const int lane = t & 63;
  const int wv = t >> 6;            // 0..7
  const int wm = wv >> 2, wn = wv & 3;   // 2 x 4 wave grid; per-wave out 128x64

  int Bi, Bj;
  tile_decode(blockIdx.x, Bi, Bj);  // triangle over 8x8 super-grid, Bi >= Bj
  const int i0 = Bi * 256, j0 = Bj * 256;
  const int y = blockIdx.y;         // 0..6
  const int kbeg = y * 1152;
  const int kend = (y == 6) ? NE : kbeg + 1152;
  bf16_t* Mp = P + ((size_t)blockIdx.x * NSPLIT1 + y) * 65536;

  f32x16 acc[4][2] = {};

  // staging: physical 8-elem slot s=(t&7) of row r holds logical k-block (s+r)&7
  const int lrow = t >> 3;                        // 0..63 (+64 per it)
  const int cb = ((t & 7) + lrow) & 7;            // swizzled global k-block
  const bf16_t* Ag = A + (size_t)(i0 + lrow) * NE + cb * 8;
  const bf16_t* Bg = B + (size_t)(j0 + lrow) * NE + cb * 8;

  for (int k0 = kbeg; k0 < kend; k0 += 64) {
    __syncthreads();
#pragma unroll
    for (int it = 0; it < 4; ++it) {
      load_lds16(Ag + (size_t)(it * 64) * NE + k0, (char*)As + it * 8192 + t * 16);
      load_lds16(Bg + (size_t)(it * 64) * NE + k0, (char*)Bs + it * 8192 + t * 16);
    }
    __syncthreads();
#pragma unroll
    for (int kk = 0; kk < 64; kk += 16) {
      bf16x8 af[4], bfr[2];
#pragma unroll
      for (int mt = 0; mt < 4; ++mt) {
        int row = wm * 128 + mt * 32 + (lane & 31);
        int sw = (((kk >> 3) + (lane >> 5)) - row) & 7;
        af[mt] = *(const bf16x8*)&As[row * 64 + sw * 8];
      }
#pragma unroll
      for (int nt = 0; nt < 2; ++nt) {
        int row = wn * 64 + nt * 32 + (lane & 31);
        int sw = (((kk >> 3) + (lane >> 5)) - row) & 7;
        bfr[nt] = *(const bf16x8*)&Bs[row * 64 + sw * 8];
      }
#pragma unroll
      for (int mt = 0; mt < 4; ++mt)
#pragma unroll
        for (int nt = 0; nt < 2; ++nt)
          acc[mt][nt] = __builtin_amdgcn_mfma_f32_32x32x16_bf16(af[mt], bfr[nt], acc[mt][nt], 0, 0, 0);
    }
  }

  // C/D layout (32x32): col = lane&31, row = (reg&3) + 8*(reg>>2) + 4*(lane>>5)
#pragma unroll
  for (int mt = 0; mt < 4; ++mt) {
#pragma unroll
    for (int nt = 0; nt < 2; ++nt) {
      int tc = wn * 64 + nt * 32 + (lane & 31);
#pragma unroll
      for (int reg = 0; reg < 16; ++reg) {
        int tr = wm * 128 + mt * 32 + (reg & 3) + 8 * (reg >> 2) + 4 * (lane >> 5);
        Mp[tr * 256 + tc] = (bf16_t)acc[mt][nt][reg];
      }
    }
  }
}

// adjA_bf[i,j] = bf16( (i==j ? 1 : sum_s P[..][i,j]) * adj_v[i,j] ), both triangles.
// 136 blocks over 128^2 tri-tiles (quadrants of the 256^2 super-tiles).
__global__ void k_mask(const bf16_t* __restrict__ P, const float* __restrict__ adj_v,
                       bf16_t* __restrict__ adjA) {
  __shared__ float Ms[128 * 129];
  const int t = threadIdx.x;
  int bi, bj;
  tile_decode(blockIdx.x, bi, bj);           // 128-tile triangle, bi >= bj
  const int i0 = bi * 128, j0 = bj * 128;
  const bool diag = (bi == bj);
  // locate quadrant (qa,qb) of super-tile (Bi,Bj) in P[super][split][256][256]
  const int Bi = bi >> 1, Bj = bj >> 1;
  const int qa = bi & 1, qb = bj & 1;
  const int st = Bi * (Bi + 1) / 2 + Bj;
  const bf16_t* Pt = P + (size_t)st * (NSPLIT1 * 65536)
                   + (size_t)(qa * 128) * 256 + qb * 128;
#pragma unroll 2
  for (int c = 0; c < 8; ++c) {
    int e0 = (c * 256 + t) * 8;              // element index within 128x128 quadrant
    int r = e0 >> 7, col = e0 & 127;
    float v[8] = {};
#pragma unroll
    for (int s = 0; s < NSPLIT1; ++s) {
      bf16x8 pv = *(const bf16x8*)(Pt + (size_t)s * 65536 + r * 256 + col);
#pragma unroll
      for (int u = 0; u < 8; ++u) v[u] += (float)pv[u];
    }
    size_t g = (size_t)(i0 + r) * NV + j0 + col;
    f32x4 av0 = *(const f32x4*)(adj_v + g);
    f32x4 av1 = *(const f32x4*)(adj_v + g + 4);
    bf16x8 outv;
#pragma unroll
    for (int u = 0; u < 8; ++u) {
      float vv = (diag && r == col + u) ? 1.0f : v[u];
      outv[u] = (bf16_t)(vv * (u < 4 ? av0[u] : av1[u - 4]));
    }
    *(bf16x8*)(adjA + g) = outv;
    if (!diag) {
#pragma unroll
      for (int u = 0; u < 8; ++u) Ms[(col + u) * 129 + r] = v[u];
    }
  }
  if (diag) return;
  __syncthreads();
#pragma unroll 2
  for (int c = 0; c < 8; ++c) {
    int e0 = (c * 256 + t) * 8;
    int r = e0 >> 7, col = e0 & 127;
    size_t g = (size_t)(j0 + r) * NV + i0 + col;
    f32x4 av0 = *(const f32x4*)(adj_v + g);
    f32x4 av1 = *(const f32x4*)(adj_v + g + 4);
    bf16x8 outv;
#pragma unroll
    for (int u = 0; u < 8; ++u)
      outv[u] = (bf16_t)(Ms[r * 129 + col + u] * (u < 4 ? av0[u] : av1[u - 4]));
    *(bf16x8*)(adjA + g) = outv;
  }
}

// P2[split][i][o] = partial of adjA @ HW^T over K chunk of KCHUNK2. grid (16, KSPLIT2).
__global__ void k_gemm2(const bf16_t* __restrict__ adjA, const bf16_t* __restrict__ HWt,
                        float* __restrict__ P2) {
  __shared__ bf16_t As[128 * 64];
  __shared__ bf16_t Bs[128 * 64];
  const int t = threadIdx.x;
  const int lane = t & 63;
  const int wv = t >> 6;
  const int wm = wv >> 1, wn = wv & 1;
  const int i0 = blockIdx.x * 128;
  const int kbeg = blockIdx.y * KCHUNK2;
  float* Pp = P2 + (size_t)blockIdx.y * (NV * 128);

  f32x4 acc[4][4] = {};

  const int lrow = t >> 3;
  const int cb = ((t & 7) + lrow) & 7;
  const bf16_t* Ag = adjA + (size_t)(i0 + lrow) * NV + cb * 8;
  const bf16_t* Bg = HWt + (size_t)lrow * NV + cb * 8;

  for (int k0 = kbeg; k0 < kbeg + KCHUNK2; k0 += 64) {
    __syncthreads();
#pragma unroll
    for (int it = 0; it < 4; ++it) {
      load_lds16(Ag + (size_t)(it * 32) * NV + k0, (char*)As + (it * 256 + t) * 16);
      load_lds16(Bg + (size_t)(it * 32) * NV + k0, (char*)Bs + (it * 256 + t) * 16);
    }
    __syncthreads();
#pragma unroll
    for (int kk = 0; kk < 64; kk += 32) {
      bf16x8 af[4], bfr[4];
#pragma unroll
      for (int mt = 0; mt < 4; ++mt) {
        int row = wm * 64 + mt * 16 + (lane & 15);
        int sw = (((kk >> 3) + (lane >> 4)) - row) & 7;
        af[mt] = *(const bf16x8*)&As[row * 64 + sw * 8];
      }
#pragma unroll
      for (int nt = 0; nt < 4; ++nt) {
        int row = wn * 64 + nt * 16 + (lane & 15);
        int sw = (((kk >> 3) + (lane >> 4)) - row) & 7;
        bfr[nt] = *(const bf16x8*)&Bs[row * 64 + sw * 8];
      }
#pragma unroll
      for (int mt = 0; mt < 4; ++mt)
#pragma unroll
        for (int nt = 0; nt < 4; ++nt)
          acc[mt][nt] = __builtin_amdgcn_mfma_f32_16x16x32_bf16(af[mt], bfr[nt], acc[mt][nt], 0, 0, 0);
    }
  }

#pragma unroll
  for (int mt = 0; mt < 4; ++mt) {
#pragma unroll
    for (int nt = 0; nt < 4; ++nt) {
      int gc = wn * 64 + nt * 16 + (lane & 15);   // output col o (0..127)
#pragma unroll
      for (int r = 0; r < 4; ++r) {
        int gr = i0 + wm * 64 + mt * 16 + (lane >> 4) * 4 + r;
        Pp[(size_t)gr * 128 + gc] = acc[mt][nt][r];
      }
    }
  }
}

// blocks [0,256):   out[i,o] = sum_s P2[s][i][o] + bias[o]
// blocks [256,1280): out2 = copy of H_e (fused passthrough, replaces memcpy)
__global__ void k_bias(const float* __restrict__ P2, const float* __restrict__ bias,
                       const float* __restrict__ He, float* __restrict__ out) {
  int b = blockIdx.x;
  if (b < 256) {
    int idx = (b * 256 + threadIdx.x) * 4;  // 2048*128/4 = 65536 threads
    f32x4 acc = {};
#pragma unroll
    for (int s = 0; s < KSPLIT2; ++s)
      acc += *(const f32x4*)(P2 + (size_t)s * NV * 128 + idx);
    f32x4 bb = *(const f32x4*)(bias + (idx & 127));
    *(f32x4*)(out + idx) = acc + bb;
  } else {
    size_t idx = ((size_t)(b - 256) * 256 + threadIdx.x) * 4;
    *(f32x4*)(out + (size_t)NV * 128 + idx) = *(const f32x4*)(He + idx);
  }
}

extern "C" void kernel_launch(void* const* d_in, const int* in_sizes, int n_in,
                              void* d_out, int out_size, void* d_ws, size_t ws_size,
                              hipStream_t stream) {
  const float* Hv     = (const float*)d_in[0];
  const float* He     = (const float*)d_in[1];
  // d_in[2] = adj_e : UNUSED in the node_layer branch
  const float* adj_v  = (const float*)d_in[3];
  const float* T      = (const float*)d_in[4];
  const float* weight = (const float*)d_in[5];
  const float* p      = (const float*)d_in[6];
  const float* bias   = (const float*)d_in[7];
  float* out = (float*)d_out;

  char* ws = (char*)d_ws;
  bf16_t* A_bf  = (bf16_t*)ws;                       // [0, 32M)
  bf16_t* B_bf  = (bf16_t*)(ws + 33554432);          // [32M, 64M)
  bf16_t* P1    = (bf16_t*)(ws + 67108864);          // 36*7*65536*2 = 33.0 MB
  bf16_t* adjAb = (bf16_t*)(ws + 104857600);         // [100M, +8 MB)
  float*  P2    = (float*)(ws + 113246208);          // [108M, +16 MB)
  bf16_t* HWt   = (bf16_t*)(ws + 130023424);         // [124M, +512 KB)
  float*  w     = (float*)(ws + 130547712);          // [124.5M, +32 KB)

  k_w<<<NE / 4, 256, 0, stream>>>(He, p, w);
  k_conv<<<(NV * NE / 4) / 256, 256, 0, stream>>>(T, w, A_bf, B_bf);
  k_hw<<<(NV * 128) / 256, 256, 0, stream>>>(Hv, weight, HWt);
  dim3 g1(36, NSPLIT1);
  k_gemm1<<<g1, 512, 0, stream>>>(A_bf, B_bf, P1);
  k_mask<<<136, 256, 0, stream>>>(P1, adj_v, adjAb);
  dim3 g2(NV / 128, KSPLIT2);
  k_gemm2<<<g2, 256, 0, stream>>>(adjAb, HWt, P2);
  k_bias<<<256 + (NE * 128) / (4 * 256), 256, 0, stream>>>(P2, bias, He, out);
}

// Round 4
// 450.367 us; speedup vs baseline: 1.0632x; 1.0132x over previous
//
#include <hip/hip_runtime.h>
#include <hip/hip_bf16.h>
#include <stdint.h>
#include <stddef.h>

#define NV 2048
#define NE 8192
#define NSPLIT1 7           // gemm1 K-splits: 36 super-tiles * 7 = 252 blocks = 1 round on 256 CUs
#define KSPLIT2 16          // gemm2 K-split: 16*16 = 256 blocks
#define KCHUNK2 (NV / KSPLIT2)

typedef __bf16 bf16_t;
typedef __bf16 bf16x4 __attribute__((ext_vector_type(4)));
typedef __bf16 bf16x8 __attribute__((ext_vector_type(8)));
typedef float f32x4 __attribute__((ext_vector_type(4)));
typedef float f32x16 __attribute__((ext_vector_type(16)));

__device__ static inline void load_lds16(const void* g, void* lds) {
  __builtin_amdgcn_global_load_lds(
      (const __attribute__((address_space(1))) void*)g,
      (__attribute__((address_space(3))) void*)lds,
      16, 0, 0);
}

__device__ static inline void tile_decode(int tile, int& bi, int& bj) {
  int b = (int)((sqrtf(8.f * tile + 1.f) - 1.f) * 0.5f);
  while ((b + 1) * (b + 2) / 2 <= tile) b++;
  while (b * (b + 1) / 2 > tile) b--;
  bi = b;
  bj = tile - b * (b + 1) / 2;
}

// w[e] = dot(H_e[e,:], p[:])   one wave per row
__global__ void k_w(const float* __restrict__ He, const float* __restrict__ p,
                    float* __restrict__ w) {
  int wave = threadIdx.x >> 6;
  int lane = threadIdx.x & 63;
  int e = blockIdx.x * 4 + wave;
  float v = He[(size_t)e * 128 + lane] * p[lane]
          + He[(size_t)e * 128 + 64 + lane] * p[64 + lane];
#pragma unroll
  for (int off = 32; off > 0; off >>= 1) v += __shfl_down(v, off, 64);
  if (lane == 0) w[e] = v;
}

// A[i,e] = bf16(T[i,e]*w[e]);  B[i,e] = bf16(T[i,e])
__global__ void k_conv(const float* __restrict__ T, const float* __restrict__ w,
                       bf16_t* __restrict__ A, bf16_t* __restrict__ B) {
  size_t idx = (size_t)blockIdx.x * 256 + threadIdx.x;  // one float4 each
  size_t base = idx * 4;
  int col = (int)(base & (NE - 1));
  f32x4 t = *(const f32x4*)(T + base);
  f32x4 w4 = *(const f32x4*)(w + col);
  bf16x4 a, b;
  a.x = (bf16_t)(t.x * w4.x); a.y = (bf16_t)(t.y * w4.y);
  a.z = (bf16_t)(t.z * w4.z); a.w = (bf16_t)(t.w * w4.w);
  b.x = (bf16_t)t.x; b.y = (bf16_t)t.y; b.z = (bf16_t)t.z; b.w = (bf16_t)t.w;
  *(bf16x4*)(A + base) = a;
  *(bf16x4*)(B + base) = b;
}

// HWt[o,j] = bf16( sum_k H_v[j,k] * weight[k,o] )   (transposed, bf16)
__global__ void k_hw(const float* __restrict__ Hv, const float* __restrict__ Wt,
                     bf16_t* __restrict__ HWt) {
  int t = blockIdx.x * 256 + threadIdx.x;
  int o = t & 127, j = t >> 7;
  const float* hv = Hv + (size_t)j * 128;
  float acc = 0.f;
#pragma unroll 4
  for (int k = 0; k < 128; ++k) acc += hv[k] * Wt[k * 128 + o];
  HWt[(size_t)o * NV + j] = (bf16_t)acc;
}

// P[super36][split7][256][256](bf16) partials of T*w @ T^T, lower-tri 256-super-tiles.
// grid (36, 7), 512 threads (8 waves, 2x4), BK=64, 32x32x16 MFMA, XOR-slot LDS swizzle.
// Double-buffered prefetch (T3-minimum 2-phase): STAGE(next) issued BEFORE compute(cur),
// single barrier per K-step. At 1 block/CU (128 KiB LDS) explicit dbuf is the only
// stage/compute overlap mechanism -- no co-resident block to hide the drain (m114).
__global__ void __launch_bounds__(512, 1)
k_gemm1(const bf16_t* __restrict__ A, const bf16_t* __restrict__ B,
        bf16_t* __restrict__ P) {
  __shared__ bf16_t As[2][256 * 64];
  __shared__ bf16_t Bs[2][256 * 64];
  const int t = threadIdx.x;        // 0..511
  const int lane = t & 63;
  const int wv = t >> 6;            // 0..7
  const int wm = wv >> 2, wn = wv & 3;   // 2 x 4 wave grid; per-wave out 128x64

  int Bi, Bj;
  tile_decode(blockIdx.x, Bi, Bj);  // triangle over 8x8 super-grid, Bi >= Bj
  const int i0 = Bi * 256, j0 = Bj * 256;
  const int y = blockIdx.y;         // 0..6
  const int kbeg = y * 1152;
  const int kend = (y == 6) ? NE : kbeg + 1152;
  bf16_t* Mp = P + ((size_t)blockIdx.x * NSPLIT1 + y) * 65536;

  f32x16 acc[4][2] = {};

  // staging: physical 8-elem slot s=(t&7) of row r holds logical k-block (s+r)&7
  const int lrow = t >> 3;                        // 0..63 (+64 per it)
  const int cb = ((t & 7) + lrow) & 7;            // swizzled global k-block
  const bf16_t* Ag = A + (size_t)(i0 + lrow) * NE + cb * 8;
  const bf16_t* Bg = B + (size_t)(j0 + lrow) * NE + cb * 8;

#define STAGE1(buf, kk0)                                                     \
  do {                                                                       \
    _Pragma("unroll")                                                        \
    for (int it = 0; it < 4; ++it) {                                         \
      load_lds16(Ag + (size_t)(it * 64) * NE + (kk0),                        \
                 (char*)As[buf] + it * 8192 + t * 16);                       \
      load_lds16(Bg + (size_t)(it * 64) * NE + (kk0),                        \
                 (char*)Bs[buf] + it * 8192 + t * 16);                       \
    }                                                                        \
  } while (0)

  STAGE1(0, kbeg);
  __syncthreads();                  // compiler drains vmcnt(0) before s_barrier
  int cur = 0;

  for (int k0 = kbeg; k0 < kend; k0 += 64) {
    if (k0 + 64 < kend) STAGE1(cur ^ 1, k0 + 64);   // prefetch flies under MFMA
    const bf16_t* Asr = As[cur];
    const bf16_t* Bsr = Bs[cur];
#pragma unroll
    for (int kk = 0; kk < 64; kk += 16) {
      bf16x8 af[4], bfr[2];
#pragma unroll
      for (int mt = 0; mt < 4; ++mt) {
        int row = wm * 128 + mt * 32 + (lane & 31);
        int sw = (((kk >> 3) + (lane >> 5)) - row) & 7;
        af[mt] = *(const bf16x8*)&Asr[row * 64 + sw * 8];
      }
#pragma unroll
      for (int nt = 0; nt < 2; ++nt) {
        int row = wn * 64 + nt * 32 + (lane & 31);
        int sw = (((kk >> 3) + (lane >> 5)) - row) & 7;
        bfr[nt] = *(const bf16x8*)&Bsr[row * 64 + sw * 8];
      }
#pragma unroll
      for (int mt = 0; mt < 4; ++mt)
#pragma unroll
        for (int nt = 0; nt < 2; ++nt)
          acc[mt][nt] = __builtin_amdgcn_mfma_f32_32x32x16_bf16(af[mt], bfr[nt], acc[mt][nt], 0, 0, 0);
    }
    __syncthreads();                // next buffer ready; all reads of cur done
    cur ^= 1;
  }
#undef STAGE1

  // C/D layout (32x32): col = lane&31, row = (reg&3) + 8*(reg>>2) + 4*(lane>>5)
#pragma unroll
  for (int mt = 0; mt < 4; ++mt) {
#pragma unroll
    for (int nt = 0; nt < 2; ++nt) {
      int tc = wn * 64 + nt * 32 + (lane & 31);
#pragma unroll
      for (int reg = 0; reg < 16; ++reg) {
        int tr = wm * 128 + mt * 32 + (reg & 3) + 8 * (reg >> 2) + 4 * (lane >> 5);
        Mp[tr * 256 + tc] = (bf16_t)acc[mt][nt][reg];
      }
    }
  }
}

// adjA_bf[i,j] = bf16( (i==j ? 1 : sum_s P[..][i,j]) * adj_v[i,j] ), both triangles.
// 136 blocks over 128^2 tri-tiles (quadrants of the 256^2 super-tiles).
__global__ void k_mask(const bf16_t* __restrict__ P, const float* __restrict__ adj_v,
                       bf16_t* __restrict__ adjA) {
  __shared__ float Ms[128 * 129];
  const int t = threadIdx.x;
  int bi, bj;
  tile_decode(blockIdx.x, bi, bj);           // 128-tile triangle, bi >= bj
  const int i0 = bi * 128, j0 = bj * 128;
  const bool diag = (bi == bj);
  // locate quadrant (qa,qb) of super-tile (Bi,Bj) in P[super][split][256][256]
  const int Bi = bi >> 1, Bj = bj >> 1;
  const int qa = bi & 1, qb = bj & 1;
  const int st = Bi * (Bi + 1) / 2 + Bj;
  const bf16_t* Pt = P + (size_t)st * (NSPLIT1 * 65536)
                   + (size_t)(qa * 128) * 256 + qb * 128;
#pragma unroll 2
  for (int c = 0; c < 8; ++c) {
    int e0 = (c * 256 + t) * 8;              // element index within 128x128 quadrant
    int r = e0 >> 7, col = e0 & 127;
    float v[8] = {};
#pragma unroll
    for (int s = 0; s < NSPLIT1; ++s) {
      bf16x8 pv = *(const bf16x8*)(Pt + (size_t)s * 65536 + r * 256 + col);
#pragma unroll
      for (int u = 0; u < 8; ++u) v[u] += (float)pv[u];
    }
    size_t g = (size_t)(i0 + r) * NV + j0 + col;
    f32x4 av0 = *(const f32x4*)(adj_v + g);
    f32x4 av1 = *(const f32x4*)(adj_v + g + 4);
    bf16x8 outv;
#pragma unroll
    for (int u = 0; u < 8; ++u) {
      float vv = (diag && r == col + u) ? 1.0f : v[u];
      outv[u] = (bf16_t)(vv * (u < 4 ? av0[u] : av1[u - 4]));
    }
    *(bf16x8*)(adjA + g) = outv;
    if (!diag) {
#pragma unroll
      for (int u = 0; u < 8; ++u) Ms[(col + u) * 129 + r] = v[u];
    }
  }
  if (diag) return;
  __syncthreads();
#pragma unroll 2
  for (int c = 0; c < 8; ++c) {
    int e0 = (c * 256 + t) * 8;
    int r = e0 >> 7, col = e0 & 127;
    size_t g = (size_t)(j0 + r) * NV + i0 + col;
    f32x4 av0 = *(const f32x4*)(adj_v + g);
    f32x4 av1 = *(const f32x4*)(adj_v + g + 4);
    bf16x8 outv;
#pragma unroll
    for (int u = 0; u < 8; ++u)
      outv[u] = (bf16_t)(Ms[r * 129 + col + u] * (u < 4 ? av0[u] : av1[u - 4]));
    *(bf16x8*)(adjA + g) = outv;
  }
}

// P2[split][i][o] = partial of adjA @ HW^T over K chunk of KCHUNK2. grid (16, KSPLIT2).
__global__ void k_gemm2(const bf16_t* __restrict__ adjA, const bf16_t* __restrict__ HWt,
                        float* __restrict__ P2) {
  __shared__ bf16_t As[128 * 64];
  __shared__ bf16_t Bs[128 * 64];
  const int t = threadIdx.x;
  const int lane = t & 63;
  const int wv = t >> 6;
  const int wm = wv >> 1, wn = wv & 1;
  const int i0 = blockIdx.x * 128;
  const int kbeg = blockIdx.y * KCHUNK2;
  float* Pp = P2 + (size_t)blockIdx.y * (NV * 128);

  f32x4 acc[4][4] = {};

  const int lrow = t >> 3;
  const int cb = ((t & 7) + lrow) & 7;
  const bf16_t* Ag = adjA + (size_t)(i0 + lrow) * NV + cb * 8;
  const bf16_t* Bg = HWt + (size_t)lrow * NV + cb * 8;

  for (int k0 = kbeg; k0 < kbeg + KCHUNK2; k0 += 64) {
    __syncthreads();
#pragma unroll
    for (int it = 0; it < 4; ++it) {
      load_lds16(Ag + (size_t)(it * 32) * NV + k0, (char*)As + (it * 256 + t) * 16);
      load_lds16(Bg + (size_t)(it * 32) * NV + k0, (char*)Bs + (it * 256 + t) * 16);
    }
    __syncthreads();
#pragma unroll
    for (int kk = 0; kk < 64; kk += 32) {
      bf16x8 af[4], bfr[4];
#pragma unroll
      for (int mt = 0; mt < 4; ++mt) {
        int row = wm * 64 + mt * 16 + (lane & 15);
        int sw = (((kk >> 3) + (lane >> 4)) - row) & 7;
        af[mt] = *(const bf16x8*)&As[row * 64 + sw * 8];
      }
#pragma unroll
      for (int nt = 0; nt < 4; ++nt) {
        int row = wn * 64 + nt * 16 + (lane & 15);
        int sw = (((kk >> 3) + (lane >> 4)) - row) & 7;
        bfr[nt] = *(const bf16x8*)&Bs[row * 64 + sw * 8];
      }
#pragma unroll
      for (int mt = 0; mt < 4; ++mt)
#pragma unroll
        for (int nt = 0; nt < 4; ++nt)
          acc[mt][nt] = __builtin_amdgcn_mfma_f32_16x16x32_bf16(af[mt], bfr[nt], acc[mt][nt], 0, 0, 0);
    }
  }

#pragma unroll
  for (int mt = 0; mt < 4; ++mt) {
#pragma unroll
    for (int nt = 0; nt < 4; ++nt) {
      int gc = wn * 64 + nt * 16 + (lane & 15);   // output col o (0..127)
#pragma unroll
      for (int r = 0; r < 4; ++r) {
        int gr = i0 + wm * 64 + mt * 16 + (lane >> 4) * 4 + r;
        Pp[(size_t)gr * 128 + gc] = acc[mt][nt][r];
      }
    }
  }
}

// blocks [0,256):   out[i,o] = sum_s P2[s][i][o] + bias[o]
// blocks [256,1280): out2 = copy of H_e (fused passthrough, replaces memcpy)
__global__ void k_bias(const float* __restrict__ P2, const float* __restrict__ bias,
                       const float* __restrict__ He, float* __restrict__ out) {
  int b = blockIdx.x;
  if (b < 256) {
    int idx = (b * 256 + threadIdx.x) * 4;  // 2048*128/4 = 65536 threads
    f32x4 acc = {};
#pragma unroll
    for (int s = 0; s < KSPLIT2; ++s)
      acc += *(const f32x4*)(P2 + (size_t)s * NV * 128 + idx);
    f32x4 bb = *(const f32x4*)(bias + (idx & 127));
    *(f32x4*)(out + idx) = acc + bb;
  } else {
    size_t idx = ((size_t)(b - 256) * 256 + threadIdx.x) * 4;
    *(f32x4*)(out + (size_t)NV * 128 + idx) = *(const f32x4*)(He + idx);
  }
}

extern "C" void kernel_launch(void* const* d_in, const int* in_sizes, int n_in,
                              void* d_out, int out_size, void* d_ws, size_t ws_size,
                              hipStream_t stream) {
  const float* Hv     = (const float*)d_in[0];
  const float* He     = (const float*)d_in[1];
  // d_in[2] = adj_e : UNUSED in the node_layer branch
  const float* adj_v  = (const float*)d_in[3];
  const float* T      = (const float*)d_in[4];
  const float* weight = (const float*)d_in[5];
  const float* p      = (const float*)d_in[6];
  const float* bias   = (const float*)d_in[7];
  float* out = (float*)d_out;

  char* ws = (char*)d_ws;
  bf16_t* A_bf  = (bf16_t*)ws;                       // [0, 32M)
  bf16_t* B_bf  = (bf16_t*)(ws + 33554432);          // [32M, 64M)
  bf16_t* P1    = (bf16_t*)(ws + 67108864);          // 36*7*65536*2 = 33.0 MB
  bf16_t* adjAb = (bf16_t*)(ws + 104857600);         // [100M, +8 MB)
  float*  P2    = (float*)(ws + 113246208);          // [108M, +16 MB)
  bf16_t* HWt   = (bf16_t*)(ws + 130023424);         // [124M, +512 KB)
  float*  w     = (float*)(ws + 130547712);          // [124.5M, +32 KB)

  k_w<<<NE / 4, 256, 0, stream>>>(He, p, w);
  k_conv<<<(NV * NE / 4) / 256, 256, 0, stream>>>(T, w, A_bf, B_bf);
  k_hw<<<(NV * 128) / 256, 256, 0, stream>>>(Hv, weight, HWt);
  dim3 g1(36, NSPLIT1);
  k_gemm1<<<g1, 512, 0, stream>>>(A_bf, B_bf, P1);
  k_mask<<<136, 256, 0, stream>>>(P1, adj_v, adjAb);
  dim3 g2(NV / 128, KSPLIT2);
  k_gemm2<<<g2, 256, 0, stream>>>(adjAb, HWt, P2);
  k_bias<<<256 + (NE * 128) / (4 * 256), 256, 0, stream>>>(P2, bias, He, out);
}